// Round 3
// baseline (5512.871 us; speedup 1.0000x reference)
//
#include <hip/hip_runtime.h>
#include <hip/hip_fp16.h>

// ---------------- types ----------------
typedef short    bf16x8 __attribute__((ext_vector_type(8)));
typedef _Float16 f16x8  __attribute__((ext_vector_type(8)));
typedef float    f32x4  __attribute__((ext_vector_type(4)));
typedef int      i32x4  __attribute__((ext_vector_type(4)));

#define T_ 512
#define B_ 64
#define I_ 128
#define H_ 256
#define L_ 6
#define M_ 32768  // T*B

// ---- workspace offsets (bytes), all 256-aligned ----
// xgp  : [2][512][8][256][24] f16 = 100663296  (permuted, bias-folded x-gates)
// x0   : [M][128] bf16  ; yA/yB : [M][512] bf16
// wih  : bf16 copies for GEMM
// whhf : [12][768][256] f16 (row-major, B-frag friendly)
// biasg: [12][768] f32 (r,z: bih+bhh; n: bih) ; bhn: [12][256] f32 (bhh n-part)
static constexpr size_t XGP_OFF   = 0;
static constexpr size_t X0_OFF    = 100663296;
static constexpr size_t YA_OFF    = 109051904;
static constexpr size_t YB_OFF    = 142606336;
static constexpr size_t WIH0_OFF  = 176160768;
static constexpr size_t WIHR_OFF  = 176553984;
static constexpr size_t WHH_OFF   = 184418304;
static constexpr size_t BIASG_OFF = 189136896;
static constexpr size_t BHN_OFF   = 189173760;

__device__ __forceinline__ unsigned bf16r(float f) {
  unsigned u = __builtin_bit_cast(unsigned, f);
  u += 0x7fffu + ((u >> 16) & 1u);
  return u >> 16;
}

// ---------------- prep kernels ----------------
__global__ void cvt_bf16(const float* __restrict__ s, unsigned short* __restrict__ d, int n) {
  for (int i = blockIdx.x * blockDim.x + threadIdx.x; i < n; i += gridDim.x * blockDim.x)
    d[i] = (unsigned short)bf16r(s[i]);
}

// whhf[ld][g][k] = f16(w_hh[g][k]), row-major [768][256] per (layer,dir)
__global__ void prep_whh(const float* __restrict__ whh0, const float* __restrict__ whhr,
                         _Float16* __restrict__ out) {
  int i = blockIdx.x * 256 + threadIdx.x;              // 12*768*256 = 2359296 exact
  int ld = i / 196608, rem = i - ld * 196608;
  const float* src = (ld < 2) ? whh0 + (size_t)ld * 196608 : whhr + (size_t)(ld - 2) * 196608;
  out[i] = (_Float16)src[rem];
}

// biasg[ld][g]: g<512 -> bih+bhh ; 512..767 -> bih only.  bhn[ld][j] = bhh[512+j]
__global__ void prep_biasg(const float* __restrict__ bih0, const float* __restrict__ bhh0,
                           const float* __restrict__ bihr, const float* __restrict__ bhhr,
                           float* __restrict__ biasg, float* __restrict__ bhn) {
  int i = blockIdx.x * 256 + threadIdx.x;              // 12*1024 = 12288 exact
  int ld = i >> 10, p = i & 1023;
  const float* bi = (ld < 2) ? bih0 + ld * 768 : bihr + (ld - 2) * 768;
  const float* bh = (ld < 2) ? bhh0 + ld * 768 : bhhr + (ld - 2) * 768;
  if (p < 768) biasg[ld * 768 + p] = bi[p] + (p < 512 ? bh[p] : 0.0f);
  else         bhn[ld * 256 + (p - 768)] = bh[512 + (p - 768)];
}

// ---------------- GEMM: xg[m,g] = sum_k A[m,k]*W[g,k] + bias, scatter to xgp ----------------
__device__ __forceinline__ void llds16(const void* g, void* l) {
  __builtin_amdgcn_global_load_lds((const __attribute__((address_space(1))) void*)g,
                                   (__attribute__((address_space(3))) void*)l, 16, 0, 0);
}

__global__ __launch_bounds__(256)
void gemm_bt(const unsigned short* __restrict__ A,    // [M][K] bf16
             const unsigned short* __restrict__ Wl,   // [2][768][K] bf16
             __half* __restrict__ xgp,                // [2][512][8][256][24] f16
             const float* __restrict__ biasg_l,       // [2][768]
             int K) {
  const int m0 = blockIdx.x * 128;
  const int n0 = blockIdx.y * 128;
  const int d  = blockIdx.z;
  const unsigned short* W = Wl + (size_t)d * 768 * K;

  __shared__ short As[128 * 64];
  __shared__ short Bs[128 * 64];

  const int tid  = threadIdx.x;
  const int lane = tid & 63;
  const int q0   = lane >> 4, c0 = lane & 15;
  const int wv = tid >> 6;
  const int wm = wv >> 1, wn = wv & 1;   // 2x2 wave grid, 64x64 per wave

  f32x4 acc[4][4] = {};

  for (int kt = 0; kt < K; kt += 64) {
#pragma unroll
    for (int i = 0; i < 4; i++) {        // stage A tile (128x64)
      int e = i * 256 + tid;
      int r = e >> 3, c = (e & 7) << 3;
      llds16(A + (size_t)(m0 + r) * K + kt + c, &As[e * 8]);
    }
#pragma unroll
    for (int i = 0; i < 4; i++) {        // stage W tile (128x64)
      int e = i * 256 + tid;
      int r = e >> 3, c = (e & 7) << 3;
      llds16(W + (size_t)(n0 + r) * K + kt + c, &Bs[e * 8]);
    }
    __syncthreads();
#pragma unroll
    for (int kf = 0; kf < 2; ++kf) {
      bf16x8 a[4], b[4];
      const int krow = kf * 32 + (q0 << 3);
#pragma unroll
      for (int f = 0; f < 4; ++f)
        a[f] = *(const bf16x8*)&As[(wm * 64 + f * 16 + c0) * 64 + krow];
#pragma unroll
      for (int f = 0; f < 4; ++f)
        b[f] = *(const bf16x8*)&Bs[(wn * 64 + f * 16 + c0) * 64 + krow];
#pragma unroll
      for (int i = 0; i < 4; i++)
#pragma unroll
        for (int jn = 0; jn < 4; jn++)
          acc[i][jn] = __builtin_amdgcn_mfma_f32_16x16x32_bf16(a[i], b[jn], acc[i][jn], 0, 0, 0);
    }
    __syncthreads();
  }

  // epilogue: bias + scatter to xgp[d][tt][bg][tid_s][24]
  // C row = rowb + vv (vv=0..3), col = g_full; value -> (gate, j) / (tt, b)
#pragma unroll
  for (int jn = 0; jn < 4; jn++) {
    const int col = n0 + wn * 64 + jn * 16 + c0;
    const float bias = biasg_l[d * 768 + col];
    const int j = col & 255, gate = col >> 8;
    const int wj = j >> 6, c0j = j & 15, tj = (j >> 4) & 3;
#pragma unroll
    for (int i = 0; i < 4; i++) {
      const int rowb = m0 + wm * 64 + i * 16 + q0 * 4;
#pragma unroll
      for (int vp = 0; vp < 2; vp++) {
        const int row = rowb + 2 * vp;             // even
        const int ttm = row >> 6, b = row & 63;
        const int bgm = b >> 3, ml = b & 7;        // ml even; pair (ml, ml+1) same r0
        const int r0 = ml >> 1;
        const int tid_s = wj * 64 + r0 * 16 + c0j;
        const int idx = gate * 8 + tj * 2;
        size_t e = ((((size_t)d * 512 + ttm) * 8 + bgm) * 256 + tid_s) * 24 + idx;
        float f0 = acc[i][jn][2 * vp] + bias;
        float f1 = acc[i][jn][2 * vp + 1] + bias;
        *(__half2*)(xgp + e) = __floats2half2_rn(f0, f1);
      }
    }
  }
}

// ---------------- MFMA recurrent scan ----------------
// One WG = 8 chains (batch group) x 1 direction. 256 threads, 1 wave/SIMD (512-reg budget).
// Wave w owns gate-triple cols j in [64w, 64w+64): 12 col-tiles x 8 k-tiles of W_hh
// in registers (64 frags pinned to AGPRs). H (8x256 f16) in swizzled LDS double buffer.
// Batch m_loc = 2*q0 + v maps to C/A row 4*q0 + v (rows {0,1,4,5,8,9,12,13}; rest zero).
__global__ __launch_bounds__(256, 1)
void gru_mfma(const _Float16* __restrict__ whh,   // [12][768][256] f16
              const float* __restrict__ bhn_all,  // [12][256]
              const __half* __restrict__ xgp,     // [2][512][8][256][24] f16
              const float* __restrict__ h0,       // [12][64][256] f32
              unsigned short* __restrict__ yout,  // [512][64][512] bf16
              float* __restrict__ dout,           // f32 out (y + h_n)
              int layer, int last) {
  const int tid = threadIdx.x, lane = tid & 63, w = tid >> 6;
  const int q0 = lane >> 4, c0 = lane & 15;
  const int bg = blockIdx.x, d = blockIdx.y, ld = layer * 2 + d;

  __shared__ __attribute__((aligned(16))) _Float16 Hs[2][16][256];
  char* lds = (char*)&Hs[0][0][0];

  // ---- B-frags: wf[g*4+t][kt] = W[g*256+64w+16t+c0][kt*32+q0*8 .. +8] ----
  i32x4 wf[12][8];
  {
    const _Float16* wb = whh + (size_t)ld * 196608;
#pragma unroll
    for (int g = 0; g < 3; g++)
#pragma unroll
      for (int t = 0; t < 4; t++) {
        const _Float16* rp = wb + (size_t)(g * 256 + w * 64 + t * 16 + c0) * 256 + q0 * 8;
#pragma unroll
        for (int kt = 0; kt < 8; kt++)
          wf[g * 4 + t][kt] = *(const i32x4*)(rp + kt * 32);
      }
  }
  // pin first 8 tiles (g=0,1) into AGPRs: 256 a-regs, guaranteed residency
#pragma unroll
  for (int i = 0; i < 8; i++)
#pragma unroll
    for (int kt = 0; kt < 8; kt++)
      asm volatile("" : "+a"(wf[i][kt]));

  // ---- per-thread constants ----
  float bhn_t[4];
#pragma unroll
  for (int t = 0; t < 4; t++) bhn_t[t] = bhn_all[ld * 256 + w * 64 + t * 16 + c0];

  float hreg[4][2];
#pragma unroll
  for (int t = 0; t < 4; t++)
#pragma unroll
    for (int v = 0; v < 2; v++)
      hreg[t][v] = h0[(size_t)ld * 16384 + (bg * 8 + 2 * q0 + v) * 256 + (w * 64 + t * 16 + c0)];

  // A-read offsets (swizzled) and gate-write offsets
  int aoff[8];
#pragma unroll
  for (int kt = 0; kt < 8; kt++)
    aoff[kt] = (c0 * 512 + kt * 64 + q0 * 16) ^ ((c0 & 7) << 4);
  int woff[4][2];
#pragma unroll
  for (int t = 0; t < 4; t++)
#pragma unroll
    for (int v = 0; v < 2; v++) {
      int row = 4 * q0 + v;
      woff[t][v] = (row * 512 + (w * 64 + t * 16 + c0) * 2) ^ ((row & 7) << 4);
    }
  // y-path mapping
  const int yml = tid >> 5, yjj = (tid & 31) * 8;
  const int yrow = ((yml >> 1) << 2) | (yml & 1);
  const int yoff = (yrow * 512 + yjj * 2) ^ ((yrow & 7) << 4);

  // ---- zero LDS, then write h0 rows into buf0 ----
  {
    uint4* z = (uint4*)lds;
    for (int i = tid; i < 1024; i += 256) z[i] = make_uint4(0, 0, 0, 0);
  }
  __syncthreads();
  {
    const float* hp = &h0[(size_t)ld * 16384 + (bg * 8 + yml) * 256 + yjj];
    float4 f0 = *(const float4*)hp;
    float4 f1 = *(const float4*)(hp + 4);
    f16x8 hv;
    hv[0] = (_Float16)f0.x; hv[1] = (_Float16)f0.y; hv[2] = (_Float16)f0.z; hv[3] = (_Float16)f0.w;
    hv[4] = (_Float16)f1.x; hv[5] = (_Float16)f1.y; hv[6] = (_Float16)f1.z; hv[7] = (_Float16)f1.w;
    *(f16x8*)(lds + yoff) = hv;   // buf0
  }

  // ---- xg prefetch for s=0 ----
  const __half* xth = xgp + ((size_t)((d * 512) * 8 + bg) * 256 + tid) * 24;
  int tt0 = d ? 511 : 0;
  uint4 xc0 = *(const uint4*)(xth + (size_t)tt0 * 49152);
  uint4 xc1 = *(const uint4*)(xth + (size_t)tt0 * 49152 + 8);
  uint4 xc2 = *(const uint4*)(xth + (size_t)tt0 * 49152 + 16);

  __syncthreads();

#define XF(g_, t_, v_) ({                                              \
    const int e_ = (g_) * 8 + (t_) * 2 + (v_);                         \
    const int wi_ = e_ >> 1;                                           \
    unsigned u_ = (wi_ < 4) ? (&xc0.x)[wi_]                            \
                : (wi_ < 8) ? (&xc1.x)[wi_ - 4] : (&xc2.x)[wi_ - 8];   \
    u_ = ((e_) & 1) ? (u_ >> 16) : (u_ & 0xffffu);                     \
    __half2float(__ushort_as_half((unsigned short)u_)); })

  for (int s = 0; s < 512; s++) {
    const int cur = s & 1;
    const int tt = d ? 511 - s : s;
    const int sn = (s < 511) ? s + 1 : 511;
    const int ttn = d ? 511 - sn : sn;
    uint4 nx0 = *(const uint4*)(xth + (size_t)ttn * 49152);
    uint4 nx1 = *(const uint4*)(xth + (size_t)ttn * 49152 + 8);
    uint4 nx2 = *(const uint4*)(xth + (size_t)ttn * 49152 + 16);

    // A-frags from Hs[cur]
    f16x8 af[8];
    const char* rb = lds + cur * 8192;
#pragma unroll
    for (int kt = 0; kt < 8; kt++) af[kt] = *(const f16x8*)(rb + aoff[kt]);

    char* wb_lds = lds + (cur ^ 1) * 8192;
#pragma unroll
    for (int t = 0; t < 4; t++) {
      f32x4 ar = {0.f, 0.f, 0.f, 0.f}, az = {0.f, 0.f, 0.f, 0.f}, an = {0.f, 0.f, 0.f, 0.f};
#pragma unroll
      for (int kt = 0; kt < 8; kt++) {
        ar = __builtin_amdgcn_mfma_f32_16x16x32_f16(af[kt], __builtin_bit_cast(f16x8, wf[0 + t][kt]), ar, 0, 0, 0);
        az = __builtin_amdgcn_mfma_f32_16x16x32_f16(af[kt], __builtin_bit_cast(f16x8, wf[4 + t][kt]), az, 0, 0, 0);
        an = __builtin_amdgcn_mfma_f32_16x16x32_f16(af[kt], __builtin_bit_cast(f16x8, wf[8 + t][kt]), an, 0, 0, 0);
      }
#pragma unroll
      for (int v = 0; v < 2; v++) {
        const float pr = ar[v] + XF(0, t, v);
        const float pz = az[v] + XF(1, t, v);
        const float r = __builtin_amdgcn_rcpf(1.f + __builtin_amdgcn_exp2f(-1.44269504f * pr));
        const float z = __builtin_amdgcn_rcpf(1.f + __builtin_amdgcn_exp2f(-1.44269504f * pz));
        const float pn = XF(2, t, v) + r * (an[v] + bhn_t[t]);
        const float e2 = __builtin_amdgcn_exp2f(2.88539008f * pn);
        const float n = 1.f - 2.f * __builtin_amdgcn_rcpf(e2 + 1.f);
        const float h = n + z * (hreg[t][v] - n);
        hreg[t][v] = h;
        *(_Float16*)(wb_lds + woff[t][v]) = (_Float16)h;
      }
    }
    __syncthreads();

    // y-write of this step's h from Hs[cur^1] (coalesced); next step writes Hs[cur] -> no race
    {
      f16x8 hv = *(const f16x8*)(lds + (cur ^ 1) * 8192 + yoff);
      const size_t orow = ((size_t)tt * 64 + bg * 8 + yml) * 512 + (size_t)d * 256 + yjj;
      if (!last) {
        unsigned rr[4];
#pragma unroll
        for (int e = 0; e < 4; e++)
          rr[e] = bf16r((float)hv[2 * e]) | (bf16r((float)hv[2 * e + 1]) << 16);
        *(uint4*)&yout[orow] = make_uint4(rr[0], rr[1], rr[2], rr[3]);
      } else {
        float4 o0 = make_float4((float)hv[0], (float)hv[1], (float)hv[2], (float)hv[3]);
        float4 o1 = make_float4((float)hv[4], (float)hv[5], (float)hv[6], (float)hv[7]);
        *(float4*)&dout[orow] = o0;
        *(float4*)&dout[orow + 4] = o1;
      }
    }
    xc0 = nx0; xc1 = nx1; xc2 = nx2;
  }
#undef XF

  // final hidden state (full f32 precision from hreg)
#pragma unroll
  for (int t = 0; t < 4; t++)
#pragma unroll
    for (int v = 0; v < 2; v++)
      dout[16777216 + (size_t)ld * 16384 + (bg * 8 + 2 * q0 + v) * 256 + (w * 64 + t * 16 + c0)] =
          hreg[t][v];
}

// ---------------- launcher ----------------
extern "C" void kernel_launch(void* const* d_in, const int* in_sizes, int n_in,
                              void* d_out, int out_size, void* d_ws, size_t ws_size,
                              hipStream_t stream) {
  const float* x    = (const float*)d_in[0];
  const float* h0   = (const float*)d_in[1];
  const float* wih0 = (const float*)d_in[2];
  const float* whh0 = (const float*)d_in[3];
  const float* bih0 = (const float*)d_in[4];
  const float* bhh0 = (const float*)d_in[5];
  const float* wihr = (const float*)d_in[6];
  const float* whhr = (const float*)d_in[7];
  const float* bihr = (const float*)d_in[8];
  const float* bhhr = (const float*)d_in[9];

  char* ws = (char*)d_ws;
  __half*         xgp  = (__half*)(ws + XGP_OFF);
  unsigned short* x0   = (unsigned short*)(ws + X0_OFF);
  unsigned short* yA   = (unsigned short*)(ws + YA_OFF);
  unsigned short* yB   = (unsigned short*)(ws + YB_OFF);
  unsigned short* wih0b= (unsigned short*)(ws + WIH0_OFF);
  unsigned short* wihrb= (unsigned short*)(ws + WIHR_OFF);
  _Float16*       whhf = (_Float16*)(ws + WHH_OFF);
  float*          biasg= (float*)(ws + BIASG_OFF);
  float*          bhn  = (float*)(ws + BHN_OFF);
  float*          dout = (float*)d_out;

  cvt_bf16<<<4096, 256, 0, stream>>>(x, x0, M_ * I_);
  cvt_bf16<<<768, 256, 0, stream>>>(wih0, wih0b, 2 * 768 * 128);
  cvt_bf16<<<4096, 256, 0, stream>>>(wihr, wihrb, 5 * 2 * 768 * 512);
  prep_whh<<<9216, 256, 0, stream>>>(whh0, whhr, whhf);
  prep_biasg<<<48, 256, 0, stream>>>(bih0, bhh0, bihr, bhhr, biasg, bhn);

  for (int l = 0; l < L_; l++) {
    unsigned short* yw = (l & 1) ? yB : yA;                        // scan l writes
    const unsigned short* A = (l == 0) ? x0 : ((l & 1) ? yA : yB); // gemm l reads scan l-1 out
    const int K = (l == 0) ? 128 : 512;
    const unsigned short* W = (l == 0) ? wih0b : wihrb + (size_t)(l - 1) * 2 * 768 * 512;

    gemm_bt<<<dim3(256, 6, 2), 256, 0, stream>>>(A, W, xgp, biasg + (size_t)l * 1536, K);
    gru_mfma<<<dim3(8, 2), 256, 0, stream>>>(whhf, bhn, xgp, h0, yw, dout, l, l == L_ - 1);
  }
}

// Round 4
// 4395.893 us; speedup vs baseline: 1.2541x; 1.2541x over previous
//
#include <hip/hip_runtime.h>
#include <hip/hip_fp16.h>

// ---------------- types ----------------
typedef short    bf16x8 __attribute__((ext_vector_type(8)));
typedef _Float16 f16x8  __attribute__((ext_vector_type(8)));
typedef _Float16 f16x4  __attribute__((ext_vector_type(4)));
typedef float    f32x4  __attribute__((ext_vector_type(4)));
typedef int      i32x4  __attribute__((ext_vector_type(4)));

#define T_ 512
#define B_ 64
#define I_ 128
#define H_ 256
#define L_ 6
#define M_ 32768  // T*B

// ---- workspace offsets (bytes) ----
// xgp  : [2][512][16][256][12] f16 = 100663296 (permuted, bias-folded x-gates)
static constexpr size_t XGP_OFF   = 0;
static constexpr size_t X0_OFF    = 100663296;
static constexpr size_t YA_OFF    = 109051904;
static constexpr size_t YB_OFF    = 142606336;
static constexpr size_t WIH0_OFF  = 176160768;
static constexpr size_t WIHR_OFF  = 176553984;
static constexpr size_t WHH_OFF   = 184418304;
static constexpr size_t BIASG_OFF = 189136896;
static constexpr size_t BHN_OFF   = 189173760;

__device__ __forceinline__ unsigned bf16r(float f) {
  unsigned u = __builtin_bit_cast(unsigned, f);
  u += 0x7fffu + ((u >> 16) & 1u);
  return u >> 16;
}

// ---------------- prep kernels ----------------
__global__ void cvt_bf16(const float* __restrict__ s, unsigned short* __restrict__ d, int n) {
  for (int i = blockIdx.x * blockDim.x + threadIdx.x; i < n; i += gridDim.x * blockDim.x)
    d[i] = (unsigned short)bf16r(s[i]);
}

__global__ void prep_whh(const float* __restrict__ whh0, const float* __restrict__ whhr,
                         _Float16* __restrict__ out) {
  int i = blockIdx.x * 256 + threadIdx.x;              // 12*768*256 = 2359296 exact
  int ld = i / 196608, rem = i - ld * 196608;
  const float* src = (ld < 2) ? whh0 + (size_t)ld * 196608 : whhr + (size_t)(ld - 2) * 196608;
  out[i] = (_Float16)src[rem];
}

__global__ void prep_biasg(const float* __restrict__ bih0, const float* __restrict__ bhh0,
                           const float* __restrict__ bihr, const float* __restrict__ bhhr,
                           float* __restrict__ biasg, float* __restrict__ bhn) {
  int i = blockIdx.x * 256 + threadIdx.x;              // 12*1024 = 12288 exact
  int ld = i >> 10, p = i & 1023;
  const float* bi = (ld < 2) ? bih0 + ld * 768 : bihr + (ld - 2) * 768;
  const float* bh = (ld < 2) ? bhh0 + ld * 768 : bhhr + (ld - 2) * 768;
  if (p < 768) biasg[ld * 768 + p] = bi[p] + (p < 512 ? bh[p] : 0.0f);
  else         bhn[ld * 256 + (p - 768)] = bh[512 + (p - 768)];
}

// ---------------- GEMM: xg[m,g] = sum_k A[m,k]*W[g,k] + bias, scatter to xgp ----------------
__device__ __forceinline__ void llds16(const void* g, void* l) {
  __builtin_amdgcn_global_load_lds((const __attribute__((address_space(1))) void*)g,
                                   (__attribute__((address_space(3))) void*)l, 16, 0, 0);
}

__global__ __launch_bounds__(256)
void gemm_bt(const unsigned short* __restrict__ A,    // [M][K] bf16
             const unsigned short* __restrict__ Wl,   // [2][768][K] bf16
             _Float16* __restrict__ xgp,              // [2][512][16][256][12] f16
             const float* __restrict__ biasg_l,       // [2][768]
             int K) {
  const int m0 = blockIdx.x * 128;
  const int n0 = blockIdx.y * 128;
  const int d  = blockIdx.z;
  const unsigned short* W = Wl + (size_t)d * 768 * K;

  __shared__ short As[128 * 64];
  __shared__ short Bs[128 * 64];

  const int tid  = threadIdx.x;
  const int lane = tid & 63;
  const int q0   = lane >> 4, c0 = lane & 15;
  const int wv = tid >> 6;
  const int wm = wv >> 1, wn = wv & 1;   // 2x2 wave grid, 64x64 per wave

  f32x4 acc[4][4] = {};

  for (int kt = 0; kt < K; kt += 64) {
#pragma unroll
    for (int i = 0; i < 4; i++) {        // stage A tile (128x64)
      int e = i * 256 + tid;
      int r = e >> 3, c = (e & 7) << 3;
      llds16(A + (size_t)(m0 + r) * K + kt + c, &As[e * 8]);
    }
#pragma unroll
    for (int i = 0; i < 4; i++) {        // stage W tile (128x64)
      int e = i * 256 + tid;
      int r = e >> 3, c = (e & 7) << 3;
      llds16(W + (size_t)(n0 + r) * K + kt + c, &Bs[e * 8]);
    }
    __syncthreads();
#pragma unroll
    for (int kf = 0; kf < 2; ++kf) {
      bf16x8 a[4], b[4];
      const int krow = kf * 32 + (q0 << 3);
#pragma unroll
      for (int f = 0; f < 4; ++f)
        a[f] = *(const bf16x8*)&As[(wm * 64 + f * 16 + c0) * 64 + krow];
#pragma unroll
      for (int f = 0; f < 4; ++f)
        b[f] = *(const bf16x8*)&Bs[(wn * 64 + f * 16 + c0) * 64 + krow];
#pragma unroll
      for (int i = 0; i < 4; i++)
#pragma unroll
        for (int jn = 0; jn < 4; jn++)
          acc[i][jn] = __builtin_amdgcn_mfma_f32_16x16x32_bf16(a[i], b[jn], acc[i][jn], 0, 0, 0);
    }
    __syncthreads();
  }

  // epilogue: bias + scatter to xgp[d][tt][bg][tid_s][12]; slot = gate*4 + tj
  // col0 = n0+wn*64+c0 -> tj0 = 0, so jn is tj directly; 4 slots contiguous = 8B store
  _Float16* xg_d = xgp + (size_t)d * 25165824;
  const int col0 = n0 + wn * 64 + c0;
  const int gate = col0 >> 8;
  const int wj = (col0 & 255) >> 6;
  float bias[4];
#pragma unroll
  for (int jn = 0; jn < 4; jn++) bias[jn] = biasg_l[d * 768 + col0 + jn * 16];
#pragma unroll
  for (int i = 0; i < 4; i++) {
    const int rowb = m0 + wm * 64 + i * 16 + q0 * 4;   // rows rowb..rowb+3, same tt/bg
    const int tt = rowb >> 6, bgm = (rowb & 63) >> 2;
    _Float16* dst = xg_d + ((size_t)tt * 16 + bgm) * 3072 + gate * 4;
#pragma unroll
    for (int v = 0; v < 4; v++) {
      const int tid_s = wj * 64 + v * 16 + c0;
      f16x4 pk;
#pragma unroll
      for (int jn = 0; jn < 4; jn++) pk[jn] = (_Float16)(acc[i][jn][v] + bias[jn]);
      *(f16x4*)(dst + tid_s * 12) = pk;
    }
  }
}

// ---------------- MFMA recurrent scan ----------------
// One WG = 4 chains x 1 direction -> 32 WGs. 256 threads, 1 wave/SIMD.
// Batch m at A/C row 4m (lane quarter q0 = batch, acc v=0 valid).
// Wave w owns gate cols [64w,64w+64): 12 col-tiles x 8 k-tiles in regs (64 frags AGPR).
// Raw s_barrier + lgkmcnt(0) only: xg loads (2-step pipeline) and y stores stay in
// flight across barriers (no vmcnt(0) drain).
#define MFMA16(af, bf, cc) __builtin_amdgcn_mfma_f32_16x16x32_f16((af), __builtin_bit_cast(f16x8, (bf)), (cc), 0, 0, 0)

__global__ __launch_bounds__(256, 1)
void gru_mfma4(const _Float16* __restrict__ whh,   // [12][768][256] f16
               const float* __restrict__ bhn_all,  // [12][256]
               const __half* __restrict__ xgp,     // [2][512][16][256][12] f16
               const float* __restrict__ h0,       // [12][64][256] f32
               unsigned short* __restrict__ yout,  // [512][64][512] bf16
               float* __restrict__ dout,           // f32 out (y + h_n)
               int layer, int last) {
  const int tid = threadIdx.x, lane = tid & 63, w = tid >> 6;
  const int q0 = lane >> 4, c0 = lane & 15;
  const int bg = blockIdx.x, d = blockIdx.y, ld = layer * 2 + d;

  __shared__ __attribute__((aligned(16))) _Float16 Hs[2][16][256];  // 16KB
  char* lds = (char*)&Hs[0][0][0];

  // ---- B-frags: wf[g*4+t][kt] = W[g*256+64w+16t+c0][kt*32+q0*8 .. +8] ----
  i32x4 wf[12][8];
  {
    const _Float16* wb = whh + (size_t)ld * 196608;
#pragma unroll
    for (int g = 0; g < 3; g++)
#pragma unroll
      for (int t = 0; t < 4; t++) {
        const _Float16* rp = wb + (size_t)(g * 256 + w * 64 + t * 16 + c0) * 256 + q0 * 8;
#pragma unroll
        for (int kt = 0; kt < 8; kt++)
          wf[g * 4 + t][kt] = *(const i32x4*)(rp + kt * 32);
      }
  }
#pragma unroll
  for (int i = 0; i < 8; i++)         // pin 64 frags (g=0,1) to AGPRs
#pragma unroll
    for (int kt = 0; kt < 8; kt++)
      asm volatile("" : "+a"(wf[i][kt]));

  float bhn_t[4];
#pragma unroll
  for (int t = 0; t < 4; t++) bhn_t[t] = bhn_all[ld * 256 + w * 64 + t * 16 + c0];

  float hreg[4];
#pragma unroll
  for (int t = 0; t < 4; t++)
    hreg[t] = h0[(size_t)ld * 16384 + (bg * 4 + q0) * 256 + (w * 64 + t * 16 + c0)];

  // offsets (buffer-relative, bytes)
  int aoff[8];
#pragma unroll
  for (int kt = 0; kt < 8; kt++)
    aoff[kt] = (c0 * 512 + kt * 64 + q0 * 16) ^ ((c0 & 7) << 4);
  int woff[4];
#pragma unroll
  for (int t = 0; t < 4; t++)
    woff[t] = (4 * q0 * 512 + (w * 64 + t * 16 + c0) * 2) ^ (((4 * q0) & 7) << 4);
  const int yml = tid >> 6, yjj = (tid & 63) * 4;
  const int yoff = (4 * yml * 512 + yjj * 2) ^ (((4 * yml) & 7) << 4);

  // ---- zero LDS (rows != 4m stay zero forever) ----
  {
    uint4* z = (uint4*)lds;
#pragma unroll
    for (int i = 0; i < 4; i++) z[tid + i * 256] = make_uint4(0, 0, 0, 0);
  }
  __syncthreads();
#pragma unroll
  for (int t = 0; t < 4; t++)
    *(_Float16*)(lds + woff[t]) = (_Float16)hreg[t];   // buf0 = h0

  // ---- xg 2-step pipeline ----
  const __half* xth = xgp + (size_t)d * 25165824 + ((size_t)bg * 256 + tid) * 12;
  const int ttA0 = d ? 511 : 0, ttB0 = d ? 510 : 1;
  uint4 xa4 = *(const uint4*)(xth + (size_t)ttA0 * 49152);
  uint2 xa2 = *(const uint2*)(xth + (size_t)ttA0 * 49152 + 8);
  uint4 xb4 = *(const uint4*)(xth + (size_t)ttB0 * 49152);
  uint2 xb2 = *(const uint2*)(xth + (size_t)ttB0 * 49152 + 8);

  asm volatile("s_waitcnt lgkmcnt(0)" ::: "memory");
  __builtin_amdgcn_s_barrier();
  __builtin_amdgcn_sched_barrier(0);

#define XF(X4, X2, g_, t_) ({                                          \
    unsigned u_ = ((g_) < 2) ? (&X4.x)[((g_) * 4 + (t_)) >> 1]         \
                             : (&X2.x)[(t_) >> 1];                     \
    u_ = ((t_) & 1) ? (u_ >> 16) : (u_ & 0xffffu);                     \
    __half2float(__ushort_as_half((unsigned short)u_)); })

#define STEP(CUR, X4, X2, S_)                                                     \
  {                                                                               \
    const int s_ = (S_);                                                          \
    const int tt_ = d ? 511 - s_ : s_;                                            \
    f32x4 ar[4] = {}, az[4] = {}, an4[4] = {};                                    \
    const char* rb_ = lds + (CUR) * 8192;                                         \
    _Pragma("unroll")                                                             \
    for (int kt = 0; kt < 8; kt++) {                                              \
      f16x8 af_ = *(const f16x8*)(rb_ + aoff[kt]);                                \
      _Pragma("unroll")                                                           \
      for (int t = 0; t < 4; t++) {                                               \
        ar[t]  = MFMA16(af_, wf[t][kt], ar[t]);                                   \
        az[t]  = MFMA16(af_, wf[4 + t][kt], az[t]);                               \
        an4[t] = MFMA16(af_, wf[8 + t][kt], an4[t]);                              \
      }                                                                           \
    }                                                                             \
    char* wb_ = lds + (((CUR) ^ 1)) * 8192;                                       \
    _Pragma("unroll")                                                             \
    for (int t = 0; t < 4; t++) {                                                 \
      const float pr = ar[t][0] + XF(X4, X2, 0, t);                               \
      const float pz = az[t][0] + XF(X4, X2, 1, t);                               \
      const float xn = XF(X4, X2, 2, t);                                          \
      const float r = __builtin_amdgcn_rcpf(1.f + __builtin_amdgcn_exp2f(-1.44269504f * pr)); \
      const float z = __builtin_amdgcn_rcpf(1.f + __builtin_amdgcn_exp2f(-1.44269504f * pz)); \
      const float pn = xn + r * (an4[t][0] + bhn_t[t]);                           \
      const float e2 = __builtin_amdgcn_exp2f(2.88539008f * pn);                  \
      const float n = 1.f - 2.f * __builtin_amdgcn_rcpf(e2 + 1.f);                \
      const float h = n + z * (hreg[t] - n);                                      \
      hreg[t] = h;                                                                \
      *(_Float16*)(wb_ + woff[t]) = (_Float16)h;                                  \
    }                                                                             \
    {                                                                             \
      const int sp_ = (s_ + 2 <= 511) ? s_ + 2 : s_;                              \
      const int tp_ = d ? 511 - sp_ : sp_;                                        \
      X4 = *(const uint4*)(xth + (size_t)tp_ * 49152);                            \
      X2 = *(const uint2*)(xth + (size_t)tp_ * 49152 + 8);                        \
    }                                                                             \
    asm volatile("s_waitcnt lgkmcnt(0)" ::: "memory");                            \
    __builtin_amdgcn_s_barrier();                                                 \
    __builtin_amdgcn_sched_barrier(0);                                            \
    {                                                                             \
      f16x4 hv_ = *(const f16x4*)(lds + (((CUR) ^ 1)) * 8192 + yoff);             \
      const size_t orow_ = ((size_t)tt_ * 64 + bg * 4 + yml) * 512 + (size_t)d * 256 + yjj; \
      if (!last) {                                                                \
        unsigned r0_ = bf16r((float)hv_[0]) | (bf16r((float)hv_[1]) << 16);       \
        unsigned r1_ = bf16r((float)hv_[2]) | (bf16r((float)hv_[3]) << 16);       \
        *(uint2*)&yout[orow_] = make_uint2(r0_, r1_);                             \
      } else {                                                                    \
        *(float4*)&dout[orow_] =                                                  \
            make_float4((float)hv_[0], (float)hv_[1], (float)hv_[2], (float)hv_[3]); \
      }                                                                           \
    }                                                                             \
  }

  for (int s2 = 0; s2 < 512; s2 += 2) {
    STEP(0, xa4, xa2, s2);
    STEP(1, xb4, xb2, s2 + 1);
  }
#undef STEP
#undef XF

  // final hidden state (full f32 precision)
#pragma unroll
  for (int t = 0; t < 4; t++)
    dout[16777216 + (size_t)ld * 16384 + (bg * 4 + q0) * 256 + (w * 64 + t * 16 + c0)] = hreg[t];
}

// ---------------- launcher ----------------
extern "C" void kernel_launch(void* const* d_in, const int* in_sizes, int n_in,
                              void* d_out, int out_size, void* d_ws, size_t ws_size,
                              hipStream_t stream) {
  const float* x    = (const float*)d_in[0];
  const float* h0   = (const float*)d_in[1];
  const float* wih0 = (const float*)d_in[2];
  const float* whh0 = (const float*)d_in[3];
  const float* bih0 = (const float*)d_in[4];
  const float* bhh0 = (const float*)d_in[5];
  const float* wihr = (const float*)d_in[6];
  const float* whhr = (const float*)d_in[7];
  const float* bihr = (const float*)d_in[8];
  const float* bhhr = (const float*)d_in[9];

  char* ws = (char*)d_ws;
  _Float16*       xgp  = (_Float16*)(ws + XGP_OFF);
  unsigned short* x0   = (unsigned short*)(ws + X0_OFF);
  unsigned short* yA   = (unsigned short*)(ws + YA_OFF);
  unsigned short* yB   = (unsigned short*)(ws + YB_OFF);
  unsigned short* wih0b= (unsigned short*)(ws + WIH0_OFF);
  unsigned short* wihrb= (unsigned short*)(ws + WIHR_OFF);
  _Float16*       whhf = (_Float16*)(ws + WHH_OFF);
  float*          biasg= (float*)(ws + BIASG_OFF);
  float*          bhn  = (float*)(ws + BHN_OFF);
  float*          dout = (float*)d_out;

  cvt_bf16<<<4096, 256, 0, stream>>>(x, x0, M_ * I_);
  cvt_bf16<<<768, 256, 0, stream>>>(wih0, wih0b, 2 * 768 * 128);
  cvt_bf16<<<4096, 256, 0, stream>>>(wihr, wihrb, 5 * 2 * 768 * 512);
  prep_whh<<<9216, 256, 0, stream>>>(whh0, whhr, whhf);
  prep_biasg<<<48, 256, 0, stream>>>(bih0, bhh0, bihr, bhhr, biasg, bhn);

  for (int l = 0; l < L_; l++) {
    unsigned short* yw = (l & 1) ? yB : yA;                        // scan l writes
    const unsigned short* A = (l == 0) ? x0 : ((l & 1) ? yA : yB); // gemm l reads scan l-1 out
    const int K = (l == 0) ? 128 : 512;
    const unsigned short* W = (l == 0) ? wih0b : wihrb + (size_t)(l - 1) * 2 * 768 * 512;

    gemm_bt<<<dim3(256, 6, 2), 256, 0, stream>>>(A, W, xgp, biasg + (size_t)l * 1536, K);
    gru_mfma4<<<dim3(16, 2), 256, 0, stream>>>(whhf, bhn, (const __half*)xgp, h0, yw, dout, l,
                                               l == L_ - 1);
  }
}